// Round 3
// baseline (434.318 us; speedup 1.0000x reference)
//
#include <hip/hip_runtime.h>

// Problem constants: B=4096 batches, D=100 features, T=100 timesteps, O=3 outputs.
#define NB 4096
#define ND 100
#define NT 100
#define NO 3
#define BPB 2                  // batches per block
#define THREADS 256            // 4 waves; 200 compute lanes active in phase 1
#define NROW (BPB * NT)        // 200 rows per block
#define CH 5                   // float4s per pipeline stage (25 = 5 stages of 5)
#define NCH (ND / 4 / CH)      // 5 stages

// Fused kernel, round 2 (resubmit — round-2 bench was an infra failure, not a
// kernel result): same structure as round 1 (one thread per (b,t) row,
// register accumulators, tiny LDS cur tile, in-kernel leaky scan), but phase 1
// is explicitly software-pipelined with ping-pong register buffers.
//
// Round-1 post-mortem: VALUBusy 5.7%, HBM 21%, VGPR=36 -> compiler allocated
// for max occupancy and kept only ~1-2 loads in flight per wave (measured
// ~2.5KB in flight per CU vs ~10KB needed for 6.3 TB/s). Fix: ping-pong
// buffers of 5 x-float4 + 5 u-float4 keep >=10 independent loads outstanding
// per wave at all times; __launch_bounds__(256,2) lifts the VGPR cap so the
// buffers stay in registers (rule: all array indices compile-time constant).
__global__ __launch_bounds__(THREADS, 2) void fused_kernel(
    const float* __restrict__ x, const float* __restrict__ u,
    const float* __restrict__ W, const float* __restrict__ bias,
    const float* __restrict__ beta_p, const float* __restrict__ thr_p,
    float* __restrict__ out)
{
    __shared__ float4 W4[NO][ND / 4];      // 3 x 25 float4 = 1200 B
    __shared__ float  bs[NO];
    __shared__ float  curS[BPB][NT][NO];   // 2*100*3 floats = 2400 B

    const int tid = threadIdx.x;
    const int b0  = blockIdx.x * BPB;      // grid = NB/BPB = 2048, exact

    // Stage W ([3][100] row-major, 300 floats = 75 float4) and bias.
    if (tid < NO * (ND / 4)) {
        W4[tid / (ND / 4)][tid % (ND / 4)] = ((const float4*)W)[tid];
    }
    if (tid < NO) bs[tid] = bias[tid];
    __syncthreads();

    // Phase 1: cur[b][t][o] = bias[o] + sum_d (u<x) * W[o][d], one row/thread.
    if (tid < NROW) {
        const int lb = tid / NT;           // 0..1
        const int t  = tid - lb * NT;      // 0..99
        const size_t R = (size_t)(b0 + lb) * NT + t;    // global row b*100+t
        const float4* xr = (const float4*)(x + R * ND); // R*400B -> 16B aligned
        const float4* ur = (const float4*)(u + R * ND);
        float a0 = bs[0], a1 = bs[1], a2 = bs[2];

        // Software pipeline: buffers A (current) / B (next), all statically
        // indexed via full unroll so everything stays in VGPRs.
        float4 xa[CH], ua[CH];
#pragma unroll
        for (int j = 0; j < CH; ++j) { xa[j] = xr[j]; ua[j] = ur[j]; }

#pragma unroll
        for (int c = 0; c < NCH; ++c) {
            float4 xb[CH], ub[CH];
            if (c < NCH - 1) {
#pragma unroll
                for (int j = 0; j < CH; ++j) {
                    xb[j] = xr[(c + 1) * CH + j];   // issue next-chunk loads
                    ub[j] = ur[(c + 1) * CH + j];   // before consuming current
                }
            }
#pragma unroll
            for (int j = 0; j < CH; ++j) {
                const float4 xv = xa[j];
                const float4 uv = ua[j];
                const float4 w0 = W4[0][c * CH + j]; // uniform -> LDS broadcast
                const float4 w1 = W4[1][c * CH + j];
                const float4 w2 = W4[2][c * CH + j];
                float s;
                s = (uv.x < xv.x) ? 1.0f : 0.0f;
                a0 = fmaf(s, w0.x, a0); a1 = fmaf(s, w1.x, a1); a2 = fmaf(s, w2.x, a2);
                s = (uv.y < xv.y) ? 1.0f : 0.0f;
                a0 = fmaf(s, w0.y, a0); a1 = fmaf(s, w1.y, a1); a2 = fmaf(s, w2.y, a2);
                s = (uv.z < xv.z) ? 1.0f : 0.0f;
                a0 = fmaf(s, w0.z, a0); a1 = fmaf(s, w1.z, a1); a2 = fmaf(s, w2.z, a2);
                s = (uv.w < xv.w) ? 1.0f : 0.0f;
                a0 = fmaf(s, w0.w, a0); a1 = fmaf(s, w1.w, a1); a2 = fmaf(s, w2.w, a2);
            }
            if (c < NCH - 1) {
#pragma unroll
                for (int j = 0; j < CH; ++j) { xa[j] = xb[j]; ua[j] = ub[j]; }
            }
        }
        curS[lb][t][0] = a0;
        curS[lb][t][1] = a1;
        curS[lb][t][2] = a2;
    }
    __syncthreads();

    // Phase 2: sequential leaky scan, one lane per (batch, output) = 6 lanes.
    // Nonlinear recurrence (threshold reset) -> must be serial over t.
    if (tid < BPB * NO) {
        const int lb = tid / NO;
        const int o  = tid - lb * NO;
        const int bo = (b0 + lb) * NO + o;            // column in [0, 12288)
        const float beta = beta_p[0];
        const float thr  = thr_p[0];
        float* mem_rec = out + (size_t)NT * NB * NO;
        float mem = 0.0f;
        for (int t = 0; t < NT; ++t) {
            float cv = curS[lb][t][o];
            // reset from PREVIOUS mem: heaviside(mem - thr) * thr
            float rsub = (mem > thr) ? thr : 0.0f;
            // match reference op order: ((beta*mem) + cur) - reset*thr, no FMA
            mem = __fadd_rn(__fadd_rn(__fmul_rn(beta, mem), cv), -rsub);
            out[(size_t)t * (NB * NO) + bo]     = (mem > thr) ? 1.0f : 0.0f;
            mem_rec[(size_t)t * (NB * NO) + bo] = mem;
        }
    }
}

extern "C" void kernel_launch(void* const* d_in, const int* in_sizes, int n_in,
                              void* d_out, int out_size, void* d_ws, size_t ws_size,
                              hipStream_t stream) {
    const float* x    = (const float*)d_in[0];   // [4096,100,100]
    const float* u    = (const float*)d_in[1];   // [4096,100,100]
    const float* W    = (const float*)d_in[2];   // [3,100]
    const float* bias = (const float*)d_in[3];   // [3]
    const float* beta = (const float*)d_in[4];   // scalar
    const float* thr  = (const float*)d_in[5];   // scalar
    float* out = (float*)d_out;

    fused_kernel<<<NB / BPB, THREADS, 0, stream>>>(x, u, W, bias, beta, thr, out);
}

// Round 4
// 357.504 us; speedup vs baseline: 1.2149x; 1.2149x over previous
//
#include <hip/hip_runtime.h>

// Problem constants: B=4096 batches, D=100 features, T=100 timesteps, O=3 outputs.
#define NB 4096
#define ND 100
#define NT 100
#define NO 3
#define THREADS 256
#define SPW 27      // dwords per packed spike row (25 used + 2 pad; gcd(27,32)=1 -> conflict-free)

// Round-4: back to round-0's coalesced cooperative structure (full-line cache
// consumption -> FETCH was 160MB vs 532MB for per-thread-row streaming), with
// the occupancy deficit fixed by byte-packing spikes in LDS:
//   41KB float tile -> 10.8KB packed tile => 8 blocks/CU, 32 waves/CU (max),
//   grid 4096 = exactly 2 scheduling rounds. Inter-block overlap supplies the
//   MLP that rounds 1-3 tried (and failed) to get from intra-thread pipelining
//   (compiler re-sank the ping-pong loads: VGPR stayed 36, FETCH rose 1.6x).
// Scan fused: 3 lanes read the LDS cur tile -> kills the ~59us scan kernel
// and the 4.9MB workspace round-trip.
// Numerics identical to passing rounds: spike=(u<x), fmaf chain in d-order
// (byte->float cvt is exact 0.0/1.0), scan uses same __fmul_rn/__fadd_rn order.
__global__ __launch_bounds__(THREADS, 8) void fused_kernel(
    const float* __restrict__ x, const float* __restrict__ u,
    const float* __restrict__ W, const float* __restrict__ bias,
    const float* __restrict__ beta_p, const float* __restrict__ thr_p,
    float* __restrict__ out)
{
    __shared__ unsigned int sp[NT * SPW];   // 100 rows x 27 dwords = 10.8 KB
    __shared__ float Ws[NO * ND];           // 1.2 KB
    __shared__ float bs[NO];
    __shared__ float curS[NT * 4];          // [t][o] padded to 4 -> 1.6 KB

    const int tid = threadIdx.x;
    const int b   = blockIdx.x;             // one batch per block, grid = 4096

    // Stage W (300 floats = 75 float4) and bias.
    if (tid < (NO * ND) / 4) ((float4*)Ws)[tid] = ((const float4*)W)[tid];
    if (tid < NO) bs[tid] = bias[tid];

    // Phase 1: coalesced float4 loads, pack spikes as bytes into LDS.
    // 2500 chunks on 256 threads; consecutive lanes -> consecutive addresses,
    // every fetched line fully consumed immediately (no L1/L2 thrash).
    const float4* x4 = (const float4*)(x + (size_t)b * (ND * ND));
    const float4* u4 = (const float4*)(u + (size_t)b * (ND * ND));
    for (int i = tid; i < (ND * ND) / 4; i += THREADS) {
        float4 xv = x4[i];
        float4 uv = u4[i];
        int row = i / (ND / 4);             // 25 chunks per row
        int c4  = i - row * (ND / 4);
        unsigned int p = (uv.x < xv.x ? 1u        : 0u)
                       | (uv.y < xv.y ? 0x100u    : 0u)
                       | (uv.z < xv.z ? 0x10000u  : 0u)
                       | (uv.w < xv.w ? 0x1000000u: 0u);
        sp[row * SPW + c4] = p;
    }
    __syncthreads();

    // Phase 2: 300 dot tasks (o = task/100 -> <=2 values per wave = free LDS
    // broadcast; t = task%100 -> bank stride 27, coprime 32 = conflict-free).
    // Sequential d-order fmaf chain, same numerics as all passing rounds.
    for (int task = tid; task < NO * NT; task += THREADS) {
        int o = task / NT;
        int t = task - o * NT;
        const unsigned int* sr = &sp[t * SPW];
        const float*        wr = &Ws[o * ND];
        float acc = bs[o];
#pragma unroll 5
        for (int j = 0; j < ND / 4; ++j) {
            unsigned int m = sr[j];
            acc = fmaf((float)( m        & 0xffu), wr[4 * j + 0], acc);  // v_cvt_f32_ubyte0
            acc = fmaf((float)((m >> 8 ) & 0xffu), wr[4 * j + 1], acc);
            acc = fmaf((float)((m >> 16) & 0xffu), wr[4 * j + 2], acc);
            acc = fmaf((float)( m >> 24        ), wr[4 * j + 3], acc);
        }
        curS[t * 4 + o] = acc;
    }
    __syncthreads();

    // Phase 3: fused leaky scan, one lane per output (3 lanes). Serial in t
    // (nonlinear threshold reset). Stores are fire-and-forget; unroll lets
    // the compiler batch the ds_reads of future t.
    if (tid < NO) {
        const int o  = tid;
        const int bo = b * NO + o;
        const float beta = beta_p[0];
        const float thr  = thr_p[0];
        float* mem_rec = out + (size_t)NT * NB * NO;
        float mem = 0.0f;
#pragma unroll 4
        for (int t = 0; t < NT; ++t) {
            float cv = curS[t * 4 + o];
            // reset from PREVIOUS mem: heaviside(mem - thr) * thr
            float rsub = (mem > thr) ? thr : 0.0f;
            // match reference op order: ((beta*mem) + cur) - reset*thr, no FMA
            mem = __fadd_rn(__fadd_rn(__fmul_rn(beta, mem), cv), -rsub);
            out[(size_t)t * (NB * NO) + bo]     = (mem > thr) ? 1.0f : 0.0f;
            mem_rec[(size_t)t * (NB * NO) + bo] = mem;
        }
    }
}

extern "C" void kernel_launch(void* const* d_in, const int* in_sizes, int n_in,
                              void* d_out, int out_size, void* d_ws, size_t ws_size,
                              hipStream_t stream) {
    const float* x    = (const float*)d_in[0];   // [4096,100,100]
    const float* u    = (const float*)d_in[1];   // [4096,100,100]
    const float* W    = (const float*)d_in[2];   // [3,100]
    const float* bias = (const float*)d_in[3];   // [3]
    const float* beta = (const float*)d_in[4];   // scalar
    const float* thr  = (const float*)d_in[5];   // scalar
    float* out = (float*)d_out;

    fused_kernel<<<NB, THREADS, 0, stream>>>(x, u, W, bias, beta, thr, out);
}